// Round 2
// baseline (447.943 us; speedup 1.0000x reference)
//
#include <hip/hip_runtime.h>
#include <hip/hip_bf16.h>

#define ENC_DIM 2048
#define DEC_DIM 512
#define ATT_DIM 512
#define BATCH   256
#define NPIX    196

typedef __attribute__((ext_vector_type(8)))  short short8;
typedef __attribute__((ext_vector_type(16))) float f32x16;

typedef const __attribute__((address_space(1))) unsigned int gu32;
typedef __attribute__((address_space(3))) unsigned int lu32;

__device__ __forceinline__ short f2bf(float x) {
    // round-to-nearest-even bf16 (inputs are finite normals)
    unsigned u = __builtin_bit_cast(unsigned, x);
    unsigned r = (u + 0x7FFFu + ((u >> 16) & 1u)) >> 16;
    return (short)r;
}

// ---------------------------------------------------------------------------
// prep: blocks [0,256)   -> att2pb[b][a] = b_enc[a] + b_dec[a] + h[b]·W_dec[:,a]
//       blocks [256,768) -> pack W_enc into bf16 MFMA B-fragment order
//                           (32x32x16): chunk c = (nt*128+kb16)*64+lane,
//                           elem j = W_enc[kb16*16+(lane>>5)*8+j][nt*32+(lane&31)]
// ---------------------------------------------------------------------------
__global__ __launch_bounds__(256) void bahdanau_prep(
    const float* __restrict__ dec_h, const float* __restrict__ W_enc,
    const float* __restrict__ b_enc, const float* __restrict__ W_dec,
    const float* __restrict__ b_dec,
    float* __restrict__ att2pb, short* __restrict__ Wpack)
{
    int blk = blockIdx.x;
    if (blk < BATCH) {
        __shared__ float hs[DEC_DIM];
        int b = blk;
        for (int i = threadIdx.x; i < DEC_DIM; i += 256) hs[i] = dec_h[b * DEC_DIM + i];
        __syncthreads();
        for (int a = threadIdx.x; a < ATT_DIM; a += 256) {
            float s = 0.f;
            #pragma unroll 8
            for (int d = 0; d < DEC_DIM; ++d) s += hs[d] * W_dec[d * ATT_DIM + a];
            att2pb[b * ATT_DIM + a] = s + b_dec[a] + b_enc[a];
        }
    } else {
        int c    = (blk - BATCH) * 256 + threadIdx.x;   // 0 .. 131071
        int lane = c & 63;
        int kb16 = (c >> 6) & 127;
        int nt   = c >> 13;
        int n     = nt * 32 + (lane & 31);
        int kbase = kb16 * 16 + (lane >> 5) * 8;
        short8 v;
        #pragma unroll
        for (int j = 0; j < 8; ++j) v[j] = f2bf(W_enc[(kbase + j) * ATT_DIM + n]);
        *reinterpret_cast<short8*>(Wpack + (size_t)c * 8) = v;
    }
}

// ---------------------------------------------------------------------------
// gemm: grid 1024 = 256 batches x 2 n-chunks x 2 row-halves; 512 thr, 8 waves.
// wave w: row-tile rt=w&3 (32 rows), col-group g=w>>2 (128 cols of the chunk).
// acc = 4 x f32x16 (64 regs) -> target 4 waves/SIMD residency.
// K streamed 64 at a time, double-buffered LDS (global_load_lds w=16),
// one barrier per K-step. Partial scores -> spart[nc][b][p].
// XCD pairing: the two nc-blocks of a (b,rh) pair sit 8 dispatch slots apart.
// ---------------------------------------------------------------------------
__global__ __launch_bounds__(512, 4) void bahdanau_gemm(
    const float* __restrict__ enc, const float* __restrict__ w_full,
    const float* __restrict__ att2pb, const short* __restrict__ Wpack,
    float* __restrict__ spart)
{
    __shared__ __align__(16) short Bs[2][16384];  // 2 x 32 KiB
    __shared__ float red[2][128];

    const int f  = blockIdx.x;
    const int nc = (f >> 3) & 1;
    const int pp = (f >> 4) * 8 + (f & 7);        // 0..511
    const int b  = pp >> 1, rh = pp & 1;

    const int tid  = threadIdx.x;
    const int lane = tid & 63;
    const int wid  = tid >> 6;
    const int rt   = wid & 3;
    const int g    = wid >> 2;

    const float* encB = enc + (size_t)b * NPIX * ENC_DIM;
    int grow = rh * 128 + rt * 32 + (lane & 31);
    if (grow > NPIX - 1) grow = NPIX - 1;
    const float* aptr = encB + (size_t)grow * ENC_DIM + ((lane >> 5) << 3);

    const short8* Wc = reinterpret_cast<const short8*>(Wpack);

    f32x16 acc[4];
    #pragma unroll
    for (int t = 0; t < 4; ++t)
        #pragma unroll
        for (int r = 0; r < 16; ++r) acc[t][r] = 0.f;

    auto STAGE = [&](int buf, int kb) {
        #pragma unroll
        for (int i = 0; i < 4; ++i) {
            int idx = tid + i * 512;              // 0..2047 16B-chunks
            int c   = idx >> 6;                   // uniform per wave
            int ln  = idx & 63;                   // == lane
            int nt   = nc * 8 + (c >> 2);
            int kb16 = kb * 4 + (c & 3);
            const void* gp = (const void*)(Wc + (size_t)(nt * 128 + kb16) * 64 + ln);
            void*       lp = (void*)(&Bs[buf][idx * 8]);
            __builtin_amdgcn_global_load_lds((gu32*)gp, (lu32*)lp, 16, 0, 0);
        }
    };

    STAGE(0, 0);
    for (int kb = 0; kb < ENC_DIM / 64; ++kb) {
        int cur = kb & 1;
        __syncthreads();                          // staged(cur) ready
        if (kb < ENC_DIM / 64 - 1) STAGE(cur ^ 1, kb + 1);   // in flight across compute
        const short* Bb = &Bs[cur][0];
        #pragma unroll
        for (int kk = 0; kk < 4; ++kk) {
            const float* ap = aptr + kb * 64 + kk * 16;
            float4 f0 = *reinterpret_cast<const float4*>(ap);
            float4 f1 = *reinterpret_cast<const float4*>(ap + 4);
            short8 afr;
            afr[0] = f2bf(f0.x); afr[1] = f2bf(f0.y);
            afr[2] = f2bf(f0.z); afr[3] = f2bf(f0.w);
            afr[4] = f2bf(f1.x); afr[5] = f2bf(f1.y);
            afr[6] = f2bf(f1.z); afr[7] = f2bf(f1.w);
            #pragma unroll
            for (int t = 0; t < 4; ++t) {
                int tt = g * 4 + t;
                short8 bfr = *reinterpret_cast<const short8*>(
                    Bb + ((tt * 4 + kk) * 64 + lane) * 8);
                acc[t] = __builtin_amdgcn_mfma_f32_32x32x16_bf16(afr, bfr, acc[t], 0, 0, 0);
            }
        }
    }

    // fold cols: relu(acc + att2) * w_full -> per-row partial over this wave's 128 cols
    float sp[16];
    #pragma unroll
    for (int r = 0; r < 16; ++r) sp[r] = 0.f;
    #pragma unroll
    for (int t = 0; t < 4; ++t) {
        int col  = nc * 256 + g * 128 + t * 32 + (lane & 31);
        float c2 = att2pb[b * ATT_DIM + col];
        float wf = w_full[col];
        #pragma unroll
        for (int r = 0; r < 16; ++r) {
            float v = acc[t][r] + c2;
            v = v > 0.f ? v : 0.f;
            sp[r] += v * wf;
        }
    }
    // reduce over the 32 col-lanes
    #pragma unroll
    for (int r = 0; r < 16; ++r) {
        float v = sp[r];
        v += __shfl_xor(v, 1);
        v += __shfl_xor(v, 2);
        v += __shfl_xor(v, 4);
        v += __shfl_xor(v, 8);
        v += __shfl_xor(v, 16);
        sp[r] = v;
    }
    if ((lane & 31) == 0) {
        #pragma unroll
        for (int r = 0; r < 16; ++r) {
            int lr = rt * 32 + (r & 3) + 8 * (r >> 2) + 4 * (lane >> 5);
            red[g][lr] = sp[r];
        }
    }
    __syncthreads();
    if (tid < 128) {
        int p = rh * 128 + tid;
        if (p < NPIX)
            spart[nc * (BATCH * 224) + b * 224 + p] = red[0][tid] + red[1][tid];
    }
}

// ---------------------------------------------------------------------------
// ctx: grid 256. Combine chunk score partials, softmax (b_full invariant),
// write alpha, stream context: thread -> one float4 column, 196-pixel loop.
// ---------------------------------------------------------------------------
__global__ __launch_bounds__(512) void bahdanau_ctx(
    const float* __restrict__ enc, const float* __restrict__ spart,
    float* __restrict__ out_ctx, float* __restrict__ out_alpha)
{
    __shared__ float al[256];
    __shared__ float msum[2];
    const int b    = blockIdx.x;
    const int tid  = threadIdx.x;
    const int lane = tid & 63;
    const int wid  = tid >> 6;

    if (tid < NPIX)
        al[tid] = spart[b * 224 + tid] + spart[BATCH * 224 + b * 224 + tid];
    else if (tid < 256)
        al[tid] = -3.4e38f;
    __syncthreads();

    if (wid == 0) {
        float s0 = al[lane], s1 = al[lane + 64], s2 = al[lane + 128], s3 = al[lane + 192];
        float m = fmaxf(fmaxf(s0, s1), fmaxf(s2, s3));
        #pragma unroll
        for (int d = 1; d <= 32; d <<= 1) m = fmaxf(m, __shfl_xor(m, d));
        float e = __expf(s0 - m) + __expf(s1 - m) + __expf(s2 - m) + __expf(s3 - m);
        #pragma unroll
        for (int d = 1; d <= 32; d <<= 1) e += __shfl_xor(e, d);
        if (lane == 0) { msum[0] = m; msum[1] = e; }
    }
    __syncthreads();
    float m    = msum[0];
    float rinv = 1.f / msum[1];
    if (tid < NPIX) {
        float a = __expf(al[tid] - m) * rinv;
        al[tid] = a;
        out_alpha[b * NPIX + tid] = a;
    }
    __syncthreads();

    float4 c4 = {0.f, 0.f, 0.f, 0.f};
    const float4* enc4 = reinterpret_cast<const float4*>(enc + (size_t)b * NPIX * ENC_DIM);
    #pragma unroll 4
    for (int p = 0; p < NPIX; ++p) {
        float a  = al[p];
        float4 v = enc4[(size_t)p * (ENC_DIM / 4) + tid];
        c4.x += a * v.x; c4.y += a * v.y; c4.z += a * v.z; c4.w += a * v.w;
    }
    reinterpret_cast<float4*>(out_ctx)[(size_t)b * (ENC_DIM / 4) + tid] = c4;
}

extern "C" void kernel_launch(void* const* d_in, const int* in_sizes, int n_in,
                              void* d_out, int out_size, void* d_ws, size_t ws_size,
                              hipStream_t stream) {
    const float* enc    = (const float*)d_in[0];
    const float* dech   = (const float*)d_in[1];
    const float* W_enc  = (const float*)d_in[2];
    const float* b_enc  = (const float*)d_in[3];
    const float* W_dec  = (const float*)d_in[4];
    const float* b_dec  = (const float*)d_in[5];
    const float* w_full = (const float*)d_in[6];
    // d_in[7] = b_full: softmax-invariant, unused.

    float* att2pb = (float*)d_ws;                              // 512 KiB
    short* Wpack  = (short*)((char*)d_ws + 512 * 1024);        // 2 MiB
    float* spart  = (float*)((char*)d_ws + 2560 * 1024);       // 2*256*224*4 = 448 KiB

    float* out_ctx   = (float*)d_out;
    float* out_alpha = out_ctx + (size_t)BATCH * ENC_DIM;

    bahdanau_prep<<<768, 256, 0, stream>>>(dech, W_enc, b_enc, W_dec, b_dec, att2pb, Wpack);
    bahdanau_gemm<<<1024, 512, 0, stream>>>(enc, w_full, att2pb, Wpack, spart);
    bahdanau_ctx<<<BATCH, 512, 0, stream>>>(enc, spart, out_ctx, out_alpha);
}